// Round 4
// baseline (433.057 us; speedup 1.0000x reference)
//
#include <hip/hip_runtime.h>

// RBDispatcher R6 — MEASUREMENT ROUND (deliberately low-parallelism launch).
//   out[0 .. n_s2)         = x[ idx_s1[ idx_s2[r] ] / top_k ]   (random gather)
//   out[n_s2 .. n_s2+n_s1) = x[ idx_s1[r - n_s2] / top_k ]      (monotone copy)
//
// Why: five structurally different kernels (R1-R5, incl. a -57MB read-traffic
// dedup) all land at dur 255+-2us, and the kernel itself has NEVER appeared in
// the rocprof top-5 (it sits just under the ~123us poison-fill dispatches), so
// its own FETCH_SIZE/WRITE_SIZE/hbm_gbps have never been observed. This round
// runs the SAME correct algorithm (R5 dedup, carry across rows) as a
// persistent 32-block kernel (128 waves, ~1MB reads in flight < ~2.4MB needed
// to saturate HBM) so it lands >130us and becomes visible with its own
// counters. Readout decides between "kernel at half BW, keep pushing" vs
// "kernel near byte-floor + fixed harness overhead = roofline".
//
// Expected: kernel row at ~150-250us, WRITE_SIZE ~196608 KB; FETCH_SIZE
// discriminates LLC-resident x (~65-80MB) vs fill-evicted (~200MB).

typedef float v4f __attribute__((ext_vector_type(4)));

__device__ __forceinline__ void load_row(const float* __restrict__ src,
                                         int lane, v4f t[8]) {
  const v4f* __restrict__ sp = (const v4f*)src;
#pragma unroll
  for (int i = 0; i < 8; ++i) t[i] = sp[lane + 64 * i];   // cached reads
}

__device__ __forceinline__ void store_row_nt(float* __restrict__ dst,
                                             int lane, const v4f t[8]) {
  v4f* __restrict__ dp = (v4f*)dst;
#pragma unroll
  for (int i = 0; i < 8; ++i)
    __builtin_nontemporal_store(t[i], dp + lane + 64 * i); // streaming writes
}

// Persistent diagnostic kernel: wave w owns contiguous rows
// [w*rows_per_wave, (w+1)*rows_per_wave). Dedup carries across all its rows.
__global__ __launch_bounds__(256, 4) void rb_dispatch_r6_diag(
    const float* __restrict__ x,
    const int* __restrict__ idx_s1,
    const int* __restrict__ idx_s2,
    const int* __restrict__ top_k_ptr,
    float* __restrict__ out,
    int n_s2, int n_rows, int rows_per_wave) {
  const int wave = threadIdx.x >> 6;
  const int lane = threadIdx.x & 63;
  const int gw = blockIdx.x * 4 + wave;

  const int r_begin = gw * rows_per_wave;
  if (r_begin >= n_rows) return;
  int r_end = r_begin + rows_per_wave;
  if (r_end > n_rows) r_end = n_rows;

  const int tk = *top_k_ptr;

  v4f t[8];
  int cur = -1;
  for (int r = r_begin; r < r_end; ++r) {
    const int s = (r < n_s2) ? (idx_s1[idx_s2[r]] / tk)
                             : (idx_s1[r - n_s2] / tk);
    if (s != cur) {                       // wave-uniform branch (dedup)
      load_row(x + (size_t)s * 2048, lane, t);
      cur = s;
    }
    store_row_nt(out + (size_t)r * 2048, lane, t);
  }
}

// Generic fallback (any d): R2 fused wave-per-row kernel.
__global__ __launch_bounds__(256) void rb_dispatch_generic(
    const float* __restrict__ x,
    const int* __restrict__ idx_s1,
    const int* __restrict__ idx_s2,
    const int* __restrict__ top_k_ptr,
    float* __restrict__ out,
    int n_s2, int n_rows, int nvec) {
  const int wave = threadIdx.x >> 6;
  const int lane = threadIdx.x & 63;
  const int row = blockIdx.x * 4 + wave;
  if (row >= n_rows) return;
  const int top_k = *top_k_ptr;
  int src;
  if (row < n_s2) src = idx_s1[idx_s2[row]] / top_k;
  else            src = idx_s1[row - n_s2] / top_k;
  const int d = nvec * 4;
  const v4f* __restrict__ sp = (const v4f*)(x + (size_t)src * (size_t)d);
  v4f* __restrict__ dp = (v4f*)(out + (size_t)row * (size_t)d);
#pragma unroll 4
  for (int i = lane; i < nvec; i += 64) {
    v4f v = sp[i];
    __builtin_nontemporal_store(v, dp + i);
  }
}

extern "C" void kernel_launch(void* const* d_in, const int* in_sizes, int n_in,
                              void* d_out, int out_size, void* d_ws, size_t ws_size,
                              hipStream_t stream) {
  const float* x      = (const float*)d_in[0];
  const int*   idx_s1 = (const int*)d_in[1];
  const int*   idx_s2 = (const int*)d_in[2];
  // d_in[3] = n_tokens (unused), d_in[4] = top_k (device scalar)
  const int*   top_k  = (const int*)d_in[4];
  float*       out    = (float*)d_out;

  const int n_s1   = in_sizes[1];       // 16384
  const int n_s2   = in_sizes[2];       // 8192
  const int n_rows = n_s1 + n_s2;       // 24576
  const int d      = out_size / n_rows; // 2048

  if (d == 2048) {
    // DIAGNOSTIC: 32 blocks x 4 waves = 128 waves, contiguous row ranges.
    const int grid = 32;
    const int total_waves = grid * 4;
    const int rows_per_wave = (n_rows + total_waves - 1) / total_waves; // 192
    rb_dispatch_r6_diag<<<grid, 256, 0, stream>>>(
        x, idx_s1, idx_s2, top_k, out, n_s2, n_rows, rows_per_wave);
  } else {
    const int nvec = d / 4;
    const int grid = (n_rows + 3) / 4;
    rb_dispatch_generic<<<grid, 256, 0, stream>>>(
        x, idx_s1, idx_s2, top_k, out, n_s2, n_rows, nvec);
  }
}

// Round 5
// 260.470 us; speedup vs baseline: 1.6626x; 1.6626x over previous
//
#include <hip/hip_runtime.h>

// RBDispatcher R7: R5 structure, CACHED stores (isolated store-policy A/B).
//   out[0 .. n_s2)         = x[ idx_s1[ idx_s2[r] ] / top_k ]   (random gather)
//   out[n_s2 .. n_s2+n_s1) = x[ idx_s1[r - n_s2] / top_k ]      (monotone copy)
//
// R6 diagnostic established (32-block persistent run, own counters):
//   FETCH_SIZE ~57MB  (= x read from HBM ~once; LLC absorbs all re-reads)
//   WRITE_SIZE 192MB  (= mandatory output bytes; no over-write)
//   => full-grid kernel (R1-R5, all ~255us dur) runs ~65us for ~261MB
//      = 4.0 TB/s effective vs 6.3 TB/s copy ceiling (floor ~41.5us).
//   Harness fixed overhead = 433.1 - 243.6 = ~189us (fill ~125 + resets).
//
// R7 change vs R5 (one line): __builtin_nontemporal_store -> plain store.
//   Rationale: nt was adopted in R2 to keep x LLC-resident, but R6's FETCH
//   proves x stays resident regardless. nt stores bypass LLC write buffering
//   (direct-to-HBM); the 6.4 TB/s poison fill uses NORMAL stores. If the nt
//   path is the 4.0-vs-6.3 TB/s rate loss, this recovers ~15us. Store policy
//   was never isolated before (R1->R2 changed structure AND policy together).

typedef float v4f __attribute__((ext_vector_type(4)));

__device__ __forceinline__ void load_row(const float* __restrict__ src,
                                         int lane, v4f t[8]) {
  const v4f* __restrict__ sp = (const v4f*)src;
#pragma unroll
  for (int i = 0; i < 8; ++i) t[i] = sp[lane + 64 * i];   // cached reads
}

__device__ __forceinline__ void store_row(float* __restrict__ dst,
                                          int lane, const v4f t[8]) {
  v4f* __restrict__ dp = (v4f*)dst;
#pragma unroll
  for (int i = 0; i < 8; ++i)
    dp[lane + 64 * i] = t[i];            // CACHED writes (LLC-buffered writeback)
}

// Fast path, d==2048. Wave g handles rows [4g, 4g+4).
__global__ __launch_bounds__(256, 4) void rb_dispatch_r7(
    const float* __restrict__ x,
    const int* __restrict__ idx_s1,
    const int* __restrict__ idx_s2,
    const int* __restrict__ top_k_ptr,
    float* __restrict__ out,
    int n_s2, int n_rows) {
  const int wave = threadIdx.x >> 6;
  const int lane = threadIdx.x & 63;
  const int r0 = (blockIdx.x * 4 + wave) * 4;
  if (r0 >= n_rows) return;
  const int tk = *top_k_ptr;

  int s[4];
#pragma unroll
  for (int k = 0; k < 4; ++k) {
    const int r = r0 + k;                       // wave-uniform -> scalarized
    s[k] = (r < n_s2) ? (idx_s1[idx_s2[r]] / tk)
                      : (idx_s1[r - n_s2] / tk);
  }

  float* __restrict__ dst = out + (size_t)r0 * 2048;

  v4f t[8];
  int cur = -1;
#pragma unroll
  for (int k = 0; k < 4; ++k) {
    if (s[k] != cur) {                          // wave-uniform dedup branch
      load_row(x + (size_t)s[k] * 2048, lane, t);
      cur = s[k];
    }
    store_row(dst + (size_t)k * 2048, lane, t);
  }
}

// Generic fallback (any d / row count): fused wave-per-row kernel.
__global__ __launch_bounds__(256) void rb_dispatch_generic(
    const float* __restrict__ x,
    const int* __restrict__ idx_s1,
    const int* __restrict__ idx_s2,
    const int* __restrict__ top_k_ptr,
    float* __restrict__ out,
    int n_s2, int n_rows, int nvec) {
  const int wave = threadIdx.x >> 6;
  const int lane = threadIdx.x & 63;
  const int row = blockIdx.x * 4 + wave;
  if (row >= n_rows) return;
  const int top_k = *top_k_ptr;
  int src;
  if (row < n_s2) src = idx_s1[idx_s2[row]] / top_k;
  else            src = idx_s1[row - n_s2] / top_k;
  const int d = nvec * 4;
  const v4f* __restrict__ sp = (const v4f*)(x + (size_t)src * (size_t)d);
  v4f* __restrict__ dp = (v4f*)(out + (size_t)row * (size_t)d);
#pragma unroll 4
  for (int i = lane; i < nvec; i += 64) {
    dp[i] = sp[i];
  }
}

extern "C" void kernel_launch(void* const* d_in, const int* in_sizes, int n_in,
                              void* d_out, int out_size, void* d_ws, size_t ws_size,
                              hipStream_t stream) {
  const float* x      = (const float*)d_in[0];
  const int*   idx_s1 = (const int*)d_in[1];
  const int*   idx_s2 = (const int*)d_in[2];
  // d_in[3] = n_tokens (unused), d_in[4] = top_k (device scalar)
  const int*   top_k  = (const int*)d_in[4];
  float*       out    = (float*)d_out;

  const int n_s1   = in_sizes[1];       // 16384
  const int n_s2   = in_sizes[2];       // 8192
  const int n_rows = n_s1 + n_s2;       // 24576
  const int d      = out_size / n_rows; // 2048

  if (d == 2048 && (n_rows & 3) == 0 && (n_s2 & 3) == 0) {
    // 16 rows per block; 24576/16 = 1536 blocks, no tail.
    const int grid = n_rows / 16;
    rb_dispatch_r7<<<grid, 256, 0, stream>>>(
        x, idx_s1, idx_s2, top_k, out, n_s2, n_rows);
  } else {
    const int nvec = d / 4;
    const int grid = (n_rows + 3) / 4;
    rb_dispatch_generic<<<grid, 256, 0, stream>>>(
        x, idx_s1, idx_s2, top_k, out, n_s2, n_rows, nvec);
  }
}

// Round 6
// 256.746 us; speedup vs baseline: 1.6867x; 1.0145x over previous
//
#include <hip/hip_runtime.h>

// RBDispatcher FINAL (= R5): fused double-gather + concat, nt stores + dedup.
//   out[0 .. n_s2)         = x[ idx_s1[ idx_s2[r] ] / top_k ]   (random gather)
//   out[n_s2 .. n_s2+n_s1) = x[ idx_s1[r - n_s2] / top_k ]      (monotone copy)
//
// ROOFLINE EVIDENCE (R1-R7 session):
//  - R6 diagnostic (32-block persistent, own rocprof counters):
//      FETCH_SIZE ~57MB  = x read from HBM ~once (LLC absorbs all re-reads)
//      WRITE_SIZE 192MiB = mandatory output bytes (no over-write)
//      => HBM traffic ~261MB = the byte floor for this op.
//  - Fixed harness overhead = 433.1(R6 dur) - 243.6(R6 kernel) ~= 189us
//    (re-poison fill ~125us @6.4TB/s + reset dispatches). Kernel-side share
//    of the 255us metric is ~66us => 4.0 TB/s effective vs 6.29 TB/s pure
//    copy ceiling; the gap is DRAM R/W-mix turnaround on interleaved
//    random-row gather reads + streaming writes.
//  - Falsified levers (all within +-2%): store policy (R2/R7: cached stores
//    260.5us, nt 254.8-255.7us), section split (R3), 2-deep load/store
//    pipeline (R4), read-traffic dedup (R5; LLC already absorbed dups),
//    occupancy/parallelism (R6 scaling).
//
// Structure: wave g owns 4 consecutive rows; one int4/int2 index load; s[] is
// wave-uniform (scalarized); 8x dwordx4 row load into regs; dedup skips the
// 8KB re-load when consecutive rows share a source (top_k=2, sorted idx_s1,
// ~57% of s1 transitions); nontemporal stores keep out from churning the LLC
// that holds x (R7 A/B: cached stores cost ~2%).

typedef float v4f __attribute__((ext_vector_type(4)));

__device__ __forceinline__ void load_row(const float* __restrict__ src,
                                         int lane, v4f t[8]) {
  const v4f* __restrict__ sp = (const v4f*)src;
#pragma unroll
  for (int i = 0; i < 8; ++i) t[i] = sp[lane + 64 * i];   // cached: x stays in LLC
}

__device__ __forceinline__ void store_row_nt(float* __restrict__ dst,
                                             int lane, const v4f t[8]) {
  v4f* __restrict__ dp = (v4f*)dst;
#pragma unroll
  for (int i = 0; i < 8; ++i)
    __builtin_nontemporal_store(t[i], dp + lane + 64 * i); // streaming writes
}

// Fast path, d==2048. Wave g handles rows [4g, 4g+4).
__global__ __launch_bounds__(256, 4) void rb_dispatch_final(
    const float* __restrict__ x,
    const int* __restrict__ idx_s1,
    const int* __restrict__ idx_s2,
    const int* __restrict__ top_k_ptr,
    float* __restrict__ out,
    int n_s2, int n_rows) {
  const int wave = threadIdx.x >> 6;
  const int lane = threadIdx.x & 63;
  const int r0 = (blockIdx.x * 4 + wave) * 4;
  if (r0 >= n_rows) return;
  const int tk = *top_k_ptr;

  int s[4];
#pragma unroll
  for (int k = 0; k < 4; ++k) {
    const int r = r0 + k;                       // wave-uniform -> scalarized
    s[k] = (r < n_s2) ? (idx_s1[idx_s2[r]] / tk)
                      : (idx_s1[r - n_s2] / tk);
  }

  float* __restrict__ dst = out + (size_t)r0 * 2048;

  v4f t[8];
  int cur = -1;
#pragma unroll
  for (int k = 0; k < 4; ++k) {
    if (s[k] != cur) {                          // wave-uniform dedup branch
      load_row(x + (size_t)s[k] * 2048, lane, t);
      cur = s[k];
    }
    store_row_nt(dst + (size_t)k * 2048, lane, t);
  }
}

// Generic fallback (any d / row count): fused wave-per-row kernel.
__global__ __launch_bounds__(256) void rb_dispatch_generic(
    const float* __restrict__ x,
    const int* __restrict__ idx_s1,
    const int* __restrict__ idx_s2,
    const int* __restrict__ top_k_ptr,
    float* __restrict__ out,
    int n_s2, int n_rows, int nvec) {
  const int wave = threadIdx.x >> 6;
  const int lane = threadIdx.x & 63;
  const int row = blockIdx.x * 4 + wave;
  if (row >= n_rows) return;
  const int top_k = *top_k_ptr;
  int src;
  if (row < n_s2) src = idx_s1[idx_s2[row]] / top_k;
  else            src = idx_s1[row - n_s2] / top_k;
  const int d = nvec * 4;
  const v4f* __restrict__ sp = (const v4f*)(x + (size_t)src * (size_t)d);
  v4f* __restrict__ dp = (v4f*)(out + (size_t)row * (size_t)d);
#pragma unroll 4
  for (int i = lane; i < nvec; i += 64) {
    v4f v = sp[i];
    __builtin_nontemporal_store(v, dp + i);
  }
}

extern "C" void kernel_launch(void* const* d_in, const int* in_sizes, int n_in,
                              void* d_out, int out_size, void* d_ws, size_t ws_size,
                              hipStream_t stream) {
  const float* x      = (const float*)d_in[0];
  const int*   idx_s1 = (const int*)d_in[1];
  const int*   idx_s2 = (const int*)d_in[2];
  // d_in[3] = n_tokens (unused), d_in[4] = top_k (device scalar)
  const int*   top_k  = (const int*)d_in[4];
  float*       out    = (float*)d_out;

  const int n_s1   = in_sizes[1];       // 16384
  const int n_s2   = in_sizes[2];       // 8192
  const int n_rows = n_s1 + n_s2;       // 24576
  const int d      = out_size / n_rows; // 2048

  if (d == 2048 && (n_rows & 3) == 0 && (n_s2 & 3) == 0) {
    // 16 rows per block; 24576/16 = 1536 blocks, no tail.
    const int grid = n_rows / 16;
    rb_dispatch_final<<<grid, 256, 0, stream>>>(
        x, idx_s1, idx_s2, top_k, out, n_s2, n_rows);
  } else {
    const int nvec = d / 4;
    const int grid = (n_rows + 3) / 4;
    rb_dispatch_generic<<<grid, 256, 0, stream>>>(
        x, idx_s1, idx_s2, top_k, out, n_s2, n_rows, nvec);
  }
}